// Round 7
// baseline (382.209 us; speedup 1.0000x reference)
//
#include <hip/hip_runtime.h>
#include <hip/hip_fp16.h>

typedef unsigned short u16;
typedef unsigned int   u32;
typedef __bf16 bf16x8 __attribute__((ext_vector_type(8)));
typedef float  f32x4  __attribute__((ext_vector_type(4)));

// ---------------- problem constants ----------------
constexpr int BB   = 16;            // batch
constexpr int S    = 4096;          // seq len
constexpr int M    = BB * S;        // 65536 rows
constexpr int H    = 512;
constexpr int DI   = 768;
constexpr int N2   = 1536;          // 2*DI
constexpr int CL   = 128;           // chunk length (rows per block)
constexpr int CKB  = S / CL;        // 32 chunks per batch (chain length)
constexpr int DTILES = 12;          // 768 / 64 d per tile
constexpr int NCHAIN = BB * DTILES; // 192 chains
constexpr int NBLK = NCHAIN * CKB;  // 6144 blocks

// ---------------- workspace layout (bytes) — total ~6.5 MB ----------------
constexpr size_t OFF_B2C    = 0;                   // u16 [1536][64] = 196608
constexpr size_t OFF_WC     = 196608;              // f32 [768] (pad to 4096)
constexpr size_t OFF_CTRL   = 200704;              // ticket(4) + mask[192]*4, pad 4096
constexpr size_t OFF_CARRYC = 204800;              // f32 [32][192][64] = 1572864
constexpr size_t OFF_CARRYV = 1777664;             // f32 [32][192][64] = 1572864
constexpr size_t OFF_PART   = 3350528;             // f32 [12][65536]  = 3145728

constexpr float L2E = 1.4426950408889634f;

__device__ __forceinline__ u16 f2bf(float f) {
  u32 u = __float_as_uint(f);
  u32 r = (u + 0x7FFFu + ((u >> 16) & 1u)) >> 16;
  return (u16)r;
}

// swizzled cvl slot (u32 [128][64]): kills 4-way conflict on activation stores
__device__ __forceinline__ int cvs(int row, int d) {
  return row * 64 + (d ^ (((row >> 2) & 3) << 4));
}

// activation: (hidden, gate) -> (c, v), all f32
__device__ __forceinline__ void act_cv(float hidden, float gate,
                                       float& cc, float& vv) {
  float eg  = __builtin_amdgcn_exp2f(gate * L2E);
  cc = __builtin_amdgcn_rcpf(1.0f + eg);            // sigmoid(-gate)
  float zz  = eg * cc;                              // sigmoid(gate)
  float gneg = __builtin_amdgcn_rcpf(
                  1.0f + __builtin_amdgcn_exp2f(-hidden * L2E));
  float gg  = (hidden >= 0.0f) ? (hidden + 0.5f) : gneg;
  vv = zz * gg;
}

// ordered pair-combine across lanes (lower-lane run precedes upper-lane run)
__device__ __forceinline__ void comb_step(float& C, float& V, int bit, int ln) {
  float Cp = __shfl_xor(C, bit);
  float Vp = __shfl_xor(V, bit);
  bool up = (ln & bit) != 0;
  V = up ? fmaf(C, Vp, V) : fmaf(Cp, V, Vp);
  C *= Cp;
}

// ---------------- prep: B2c[n][k] = bf16( (W_in @ W_hg)[k][pi(n)] ) --------
// pi: n = 32g + r : r<16 -> hidden col (16g+r) ; r>=16 -> gate col (768+16g+(r-16))
__global__ __launch_bounds__(256) void prep_b2c(const float* __restrict__ Win,
                                                const float* __restrict__ Whg,
                                                u16* __restrict__ B2c) {
  __shared__ float Wl[64][65];
  const int tid = threadIdx.x;
  const int k = tid & 63;
  const int nloc = tid >> 6;                  // 0..3
  const int n = blockIdx.x * 4 + nloc;        // 384 blocks -> 1536 n
  const int g = n >> 5, r = n & 31;
  const int col = (r < 16) ? (g * 16 + r) : (DI + g * 16 + (r - 16));
  float acc = 0.f;
  for (int jc = 0; jc < H; jc += 64) {
    const int jl = tid & 63, k0 = tid >> 6;
    #pragma unroll
    for (int s = 0; s < 16; ++s) {
      int kr = k0 + 4 * s;
      Wl[kr][jl] = Win[kr * H + jc + jl];
    }
    __syncthreads();
    #pragma unroll 8
    for (int j = 0; j < 64; ++j)
      acc = fmaf(Wl[k][j], Whg[(size_t)(jc + j) * N2 + col], acc);
    __syncthreads();
  }
  B2c[n * 64 + k] = f2bf(acc);
}

// ---------------- prep: wcomb[d] = W_out[d,:] . W_final ----------------
__global__ __launch_bounds__(256) void prep_wcomb(const float* __restrict__ Wout,
                                                  const float* __restrict__ Wfin,
                                                  float* __restrict__ wc) {
  int wv = threadIdx.x >> 6, ln = threadIdx.x & 63;
  int d = blockIdx.x * 4 + wv;                // 192 blocks -> 768 d
  const float* row = Wout + (size_t)d * H;
  float s = 0.f;
  #pragma unroll
  for (int j = 0; j < 8; ++j) {
    int k = j * 64 + ln;
    s += row[k] * Wfin[k];
  }
  #pragma unroll
  for (int off = 32; off; off >>= 1) s += __shfl_xor(s, off);
  if (ln == 0) wc[d] = s;
}

// ======== single-pass fused: GEMM + act + segment scan + decoupled lookback
__global__ __launch_bounds__(256) void fused_all(
    const float* __restrict__ x, const u16* __restrict__ B2c,
    const float* __restrict__ wcomb,
    float* __restrict__ carryC, float* __restrict__ carryV,
    u32* __restrict__ mask, u32* __restrict__ ticket,
    float* __restrict__ part) {
  __shared__ __align__(16) u16 AB[16384];  // A [0..16KB), B [16KB..32KB); later cvl u32[128][64]
  __shared__ float SCs[4][64], SVs[4][64];
  __shared__ float hin_s[64];
  __shared__ int tkt_s;
  u32* cvl = (u32*)AB;

  const int tid = threadIdx.x, wv = tid >> 6, ln = tid & 63;

  if (tid == 0)
    tkt_s = (int)__hip_atomic_fetch_add(ticket, 1u, __ATOMIC_RELAXED,
                                        __HIP_MEMORY_SCOPE_AGENT);
  __syncthreads();
  const int logical = tkt_s;
  const int c  = logical % NCHAIN;            // chain id = b*12 + nt
  const int ck = logical / NCHAIN;            // chunk in chain, 0..31 (arrival-ordered)
  const int b = c / DTILES, nt = c % DTILES;
  const int m0 = b * S + ck * CL;             // global row base

  const int wr = wv >> 1, wcol = wv & 1;
  const int lrow = ln & 15, hi4 = ln >> 4;

  // ---- stage A from x (f32 -> bf16 in regs) and B from B2c; swizzled slots
  {
    const int row = tid >> 1, ch = (tid & 1) * 32;
    const float4* gx = (const float4*)(x + (size_t)(m0 + row) * 64 + ch);
    u32 w[16];
    #pragma unroll
    for (int j = 0; j < 8; ++j) {
      float4 f = gx[j];
      w[j * 2 + 0] = f2bf(f.x) | ((u32)f2bf(f.y) << 16);
      w[j * 2 + 1] = f2bf(f.z) | ((u32)f2bf(f.w) << 16);
    }
    uint4* lA = (uint4*)AB;
    #pragma unroll
    for (int j2 = 0; j2 < 4; ++j2) {
      int q = row * 8 + (tid & 1) * 4 + j2;
      int qs = (q & ~7) | ((q & 7) ^ (row & 7));
      lA[qs] = make_uint4(w[j2 * 4], w[j2 * 4 + 1], w[j2 * 4 + 2], w[j2 * 4 + 3]);
    }
    const uint4* gB = (const uint4*)(B2c + (size_t)nt * 128 * 64);
    uint4* lB = (uint4*)(AB + 8192);
    #pragma unroll
    for (int j = 0; j < 4; ++j) {
      int q = j * 256 + tid;
      int qs = (q & ~7) | ((q & 7) ^ ((q >> 3) & 7));
      lB[qs] = gB[q];
    }
  }
  __syncthreads();

  // ---- MFMA: 128x64(A-rows for this wave-half) x 64 d
  f32x4 acc[4][4] = {};
  {
    const u16* Al = AB;
    const u16* Bl = AB + 8192;
    #pragma unroll
    for (int kk = 0; kk < 2; ++kk) {
      bf16x8 af[4], bfr[4];
      #pragma unroll
      for (int i = 0; i < 4; ++i) {
        int row = wr * 64 + i * 16 + lrow;
        af[i] = *(const bf16x8*)&Al[row * 64 + (((kk * 4 + hi4) ^ (row & 7)) << 3)];
      }
      #pragma unroll
      for (int j = 0; j < 4; ++j) {
        int row = wcol * 64 + j * 16 + lrow;
        bfr[j] = *(const bf16x8*)&Bl[row * 64 + (((kk * 4 + hi4) ^ (row & 7)) << 3)];
      }
      #pragma unroll
      for (int i = 0; i < 4; ++i)
        #pragma unroll
        for (int j = 0; j < 4; ++j)
          acc[i][j] = __builtin_amdgcn_mfma_f32_16x16x32_bf16(af[i], bfr[j], acc[i][j], 0, 0, 0);
    }
  }

  // ---- activation ONCE: packed (c,v) kept in regs; segment summaries in regs
  u32 cvp[4][2][4];
  #pragma unroll
  for (int jp = 0; jp < 2; ++jp) {
    const int d = (wcol * 2 + jp) * 16 + lrow;   // 0..63
    #pragma unroll
    for (int sl = 0; sl < 2; ++sl) {
      float Cr[2], Vr[2];
      #pragma unroll
      for (int ii = 0; ii < 2; ++ii) {
        const int i = sl * 2 + ii;
        float C = 1.f, V = 0.f;
        #pragma unroll
        for (int r = 0; r < 4; ++r) {
          float cc, vvv;
          act_cv(acc[i][2 * jp + 0][r], acc[i][2 * jp + 1][r], cc, vvv);
          __half2 p = __floats2half2_rn(cc, vvv);
          cvp[i][jp][r] = *(const u32*)&p;
          V = fmaf(cc, V, vvv);
          C *= cc;
        }
        comb_step(C, V, 16, ln);    // rows +0..3 | +4..7
        comb_step(C, V, 32, ln);    // rows +0..7 | +8..15
        Cr[ii] = C; Vr[ii] = V;
      }
      float Cs = Cr[0] * Cr[1];
      float Vs = fmaf(Cr[1], Vr[0], Vr[1]);
      if (hi4 == 0) {
        int seg = wr * 2 + sl;      // 0..3 within chunk
        SCs[seg][d] = Cs;
        SVs[seg][d] = Vs;
      }
    }
  }
  __syncthreads();   // SCs/SVs visible; staging-LDS reads done

  if (wv == 0) {
    // chunk-local aggregate over 4 segments (per channel ln)
    float C = SCs[0][ln], V = SVs[0][ln];
    #pragma unroll
    for (int s = 1; s < 4; ++s) {
      V = fmaf(SCs[s][ln], V, SVs[s][ln]);
      C *= SCs[s][ln];
    }
    // publish local aggregate (not needed for last chunk of chain)
    if (ck < CKB - 1) {
      carryC[(size_t)ck * (NCHAIN * 64) + c * 64 + ln] = C;
      carryV[(size_t)ck * (NCHAIN * 64) + c * 64 + ln] = V;
      __threadfence();
      if (ln == 0)
        __hip_atomic_fetch_or(&mask[c], 1u << ck, __ATOMIC_RELEASE,
                              __HIP_MEMORY_SCOPE_AGENT);
    }
    // decoupled lookback: wait for ALL predecessors' locals, fold ascending
    float h = 0.f;
    if (ck > 0) {
      const u32 need = (1u << ck) - 1u;
      while ((__hip_atomic_load(&mask[c], __ATOMIC_ACQUIRE,
                                __HIP_MEMORY_SCOPE_AGENT) & need) != need)
        __builtin_amdgcn_s_sleep(1);
      const float* cC = carryC + c * 64 + ln;
      const float* cV = carryV + c * 64 + ln;
      for (int p0 = 0; p0 < ck; p0 += 8) {
        float cb[8], vb[8];
        #pragma unroll
        for (int j = 0; j < 8; ++j)
          if (p0 + j < ck) {
            cb[j] = cC[(size_t)(p0 + j) * (NCHAIN * 64)];
            vb[j] = cV[(size_t)(p0 + j) * (NCHAIN * 64)];
          }
        #pragma unroll
        for (int j = 0; j < 8; ++j)
          if (p0 + j < ck) h = fmaf(cb[j], h, vb[j]);
      }
    }
    hin_s[ln] = h;
  }

  // all waves: dump packed cv to LDS (overwrites staging tile)
  #pragma unroll
  for (int i = 0; i < 4; ++i)
    #pragma unroll
    for (int jp = 0; jp < 2; ++jp) {
      const int dl = (wcol * 2 + jp) * 16 + lrow;
      #pragma unroll
      for (int r = 0; r < 4; ++r) {
        int row = wr * 64 + i * 16 + hi4 * 4 + r;
        cvl[cvs(row, dl)] = cvp[i][jp][r];
      }
    }
  __syncthreads();

  // ---- apply: wave = segment (32 rows), lane = channel
  float h = hin_s[ln];
  if (wv >= 1) h = fmaf(SCs[0][ln], h, SVs[0][ln]);
  if (wv >= 2) h = fmaf(SCs[1][ln], h, SVs[1][ln]);
  if (wv >= 3) h = fmaf(SCs[2][ln], h, SVs[2][ln]);
  const float wd = wcomb[nt * 64 + ln];
  #pragma unroll 4
  for (int tt = 0; tt < 32; ++tt) {
    const int t = wv * 32 + tt;
    u32 u = cvl[cvs(t, ln)];
    float hn;
    asm("v_fma_mix_f32 %0, %1, %2, %1 op_sel:[0,0,1] op_sel_hi:[1,0,1]"
        : "=v"(hn) : "v"(u), "v"(h));
    h = hn;
    float pv = h * wd;
    cvl[t * 64 + ((ln + t) & 63)] = __float_as_uint(pv);
  }
  __syncthreads();
  // row reduction: 2 threads per row, rotated (conflict-free) reads
  const int row = tid >> 1, half = tid & 1;
  float s = 0.f;
  #pragma unroll 8
  for (int jj = 0; jj < 32; ++jj) {
    int idx = (half * 32 + jj + row) & 63;
    s += __uint_as_float(cvl[row * 64 + idx]);
  }
  s += __shfl_xor(s, 1);
  if (half == 0) part[(size_t)nt * M + m0 + row] = s;
}

// ---------------- final: sum 12 d-tile partials ----------------
__global__ __launch_bounds__(256) void reduce12(const float* __restrict__ part,
                                                float* __restrict__ out) {
  int i = blockIdx.x * 256 + threadIdx.x;     // 65536
  float s = 0.f;
  #pragma unroll
  for (int w = 0; w < DTILES; ++w) s += part[(size_t)w * M + i];
  out[i] = s;
}

// ---------------- launcher ----------------
extern "C" void kernel_launch(void* const* d_in, const int* in_sizes, int n_in,
                              void* d_out, int out_size, void* d_ws, size_t ws_size,
                              hipStream_t stream) {
  const float* x    = (const float*)d_in[0];
  const float* Win  = (const float*)d_in[1];
  const float* Whg  = (const float*)d_in[2];
  const float* Wout = (const float*)d_in[3];
  const float* Wfin = (const float*)d_in[4];
  float* out = (float*)d_out;
  char* ws = (char*)d_ws;

  u16*   B2c    = (u16*)(ws + OFF_B2C);
  float* wc     = (float*)(ws + OFF_WC);
  u32*   ticket = (u32*)(ws + OFF_CTRL);
  u32*   mask   = (u32*)(ws + OFF_CTRL + 256);
  float* carryC = (float*)(ws + OFF_CARRYC);
  float* carryV = (float*)(ws + OFF_CARRYV);
  float* part   = (float*)(ws + OFF_PART);

  hipMemsetAsync(ws + OFF_CTRL, 0, 4096, stream);
  prep_b2c  <<<384, 256, 0, stream>>>(Win, Whg, B2c);
  prep_wcomb<<<192, 256, 0, stream>>>(Wout, Wfin, wc);
  fused_all <<<NBLK, 256, 0, stream>>>(x, B2c, wc, carryC, carryV, mask, ticket, part);
  reduce12  <<<256, 256, 0, stream>>>(part, out);
}

// Round 8
// 145.846 us; speedup vs baseline: 2.6206x; 2.6206x over previous
//
#include <hip/hip_runtime.h>
#include <hip/hip_fp16.h>

typedef unsigned short u16;
typedef unsigned int   u32;
typedef __bf16 bf16x8 __attribute__((ext_vector_type(8)));
typedef float  f32x4  __attribute__((ext_vector_type(4)));

// ---------------- problem constants ----------------
constexpr int BB   = 16;            // batch
constexpr int S    = 4096;          // seq len
constexpr int M    = BB * S;        // 65536 rows
constexpr int H    = 512;
constexpr int DI   = 768;
constexpr int N2   = 1536;          // 2*DI
constexpr int CL   = 128;           // chunk length (rows per block)
constexpr int NCHUNK = M / CL;      // 512 chunks
constexpr int SEGB  = S / 32;       // 128 segments per batch
constexpr int DTILES = 12;          // 768 / 64 d per tile
constexpr int NBLK  = NCHUNK * DTILES;  // 6144

// ---------------- workspace layout (bytes) ----------------
constexpr size_t OFF_B2C   = 0;                        // u16 [1536][64] = 196608
constexpr size_t OFF_WC    = 196608;                   // f32 [768] (pad 4096)
constexpr size_t OFF_SEGC  = 200704;                   // f32 [2048][768] = 6291456
constexpr size_t OFF_SEGVH = OFF_SEGC + 6291456;       // f32 [2048][768] (V->Hin in place)
constexpr size_t OFF_PART  = OFF_SEGVH + 6291456;      // f32 [12][65536] = 3145728
constexpr size_t OFF_AUX   = OFF_PART + 3145728;       // 15929344: XB (8.4MB) or CV (201MB)
constexpr size_t CV_BYTES  = (size_t)NBLK * 32768;     // 201326592
constexpr size_t NEED_CV   = OFF_AUX + CV_BYTES;       // 217255936

constexpr float L2E = 1.4426950408889634f;

__device__ __forceinline__ u16 f2bf(float f) {
  u32 u = __float_as_uint(f);
  u32 r = (u + 0x7FFFu + ((u >> 16) & 1u)) >> 16;
  return (u16)r;
}

// swizzled cvl slot (u32 [128][64]): kills 4-way conflict on activation stores
__device__ __forceinline__ int cvs(int row, int d) {
  return row * 64 + (d ^ (((row >> 2) & 3) << 4));
}

// activation: (hidden, gate) -> (c, v), all f32
__device__ __forceinline__ void act_cv(float hidden, float gate,
                                       float& cc, float& vv) {
  float eg  = __builtin_amdgcn_exp2f(gate * L2E);
  cc = __builtin_amdgcn_rcpf(1.0f + eg);            // sigmoid(-gate)
  float zz  = eg * cc;                              // sigmoid(gate)
  float gneg = __builtin_amdgcn_rcpf(
                  1.0f + __builtin_amdgcn_exp2f(-hidden * L2E));
  float gg  = (hidden >= 0.0f) ? (hidden + 0.5f) : gneg;
  vv = zz * gg;
}

// ordered pair-combine across lanes (lower-lane run precedes upper-lane run)
__device__ __forceinline__ void comb_step(float& C, float& V, int bit, int ln) {
  float Cp = __shfl_xor(C, bit);
  float Vp = __shfl_xor(V, bit);
  bool up = (ln & bit) != 0;
  V = up ? fmaf(C, Vp, V) : fmaf(Cp, V, Vp);
  C *= Cp;
}

// ---------------- prep: B2c[n][k] = bf16( (W_in @ W_hg)[k][pi(n)] ) --------
__global__ __launch_bounds__(256) void prep_b2c(const float* __restrict__ Win,
                                                const float* __restrict__ Whg,
                                                u16* __restrict__ B2c) {
  __shared__ float Wl[64][65];
  const int tid = threadIdx.x;
  const int k = tid & 63;
  const int nloc = tid >> 6;
  const int n = blockIdx.x * 4 + nloc;        // 384 blocks -> 1536 n
  const int g = n >> 5, r = n & 31;
  const int col = (r < 16) ? (g * 16 + r) : (DI + g * 16 + (r - 16));
  float acc = 0.f;
  for (int jc = 0; jc < H; jc += 64) {
    const int jl = tid & 63, k0 = tid >> 6;
    #pragma unroll
    for (int s = 0; s < 16; ++s) {
      int kr = k0 + 4 * s;
      Wl[kr][jl] = Win[kr * H + jc + jl];
    }
    __syncthreads();
    #pragma unroll 8
    for (int j = 0; j < 64; ++j)
      acc = fmaf(Wl[k][j], Whg[(size_t)(jc + j) * N2 + col], acc);
    __syncthreads();
  }
  B2c[n * 64 + k] = f2bf(acc);
}

// ---------------- prep: wcomb[d] = W_out[d,:] . W_final ----------------
__global__ __launch_bounds__(256) void prep_wcomb(const float* __restrict__ Wout,
                                                  const float* __restrict__ Wfin,
                                                  float* __restrict__ wc) {
  int wv = threadIdx.x >> 6, ln = threadIdx.x & 63;
  int d = blockIdx.x * 4 + wv;
  const float* row = Wout + (size_t)d * H;
  float s = 0.f;
  #pragma unroll
  for (int j = 0; j < 8; ++j) {
    int k = j * 64 + ln;
    s += row[k] * Wfin[k];
  }
  #pragma unroll
  for (int off = 32; off; off >>= 1) s += __shfl_xor(s, off);
  if (ln == 0) wc[d] = s;
}

// ======== PASS 1: stage(x f32) + GEMM + act + segment summaries =========
// MODE 0: also write xb (bf16) for recompute pass2.  MODE 1: also write cv tile.
template<int MODE>
__global__ __launch_bounds__(256) void fused_p1(
    const float* __restrict__ x, const u16* __restrict__ B2c,
    float* __restrict__ SegC, float* __restrict__ SegV,
    u32* __restrict__ cvg, u16* __restrict__ xb) {
  __shared__ __align__(16) u16 AB[16384];   // A|B staging; later cvl u32[128][64]
  u32* cvl = (u32*)AB;

  const int tid = threadIdx.x, wv = tid >> 6, ln = tid & 63;
  const int nt = blockIdx.x % DTILES, ck = blockIdx.x / DTILES;
  const int m0 = ck * CL;
  const int wr = wv >> 1, wcol = wv & 1;
  const int lrow = ln & 15, hi4 = ln >> 4;

  // ---- stage A from x (f32 -> bf16 in regs), B from B2c; swizzled slots
  {
    const int row = tid >> 1, ch = (tid & 1) * 32;
    const float4* gx = (const float4*)(x + (size_t)(m0 + row) * 64 + ch);
    u32 w[16];
    #pragma unroll
    for (int j = 0; j < 8; ++j) {
      float4 f = gx[j];
      w[j * 2 + 0] = f2bf(f.x) | ((u32)f2bf(f.y) << 16);
      w[j * 2 + 1] = f2bf(f.z) | ((u32)f2bf(f.w) << 16);
    }
    uint4* lA = (uint4*)AB;
    #pragma unroll
    for (int j2 = 0; j2 < 4; ++j2) {
      int q = row * 8 + (tid & 1) * 4 + j2;
      int qs = (q & ~7) | ((q & 7) ^ (row & 7));
      lA[qs] = make_uint4(w[j2 * 4], w[j2 * 4 + 1], w[j2 * 4 + 2], w[j2 * 4 + 3]);
    }
    if (MODE == 0) {
      uint4* gxb = (uint4*)(xb + (size_t)(m0 + row) * 64 + ch);
      #pragma unroll
      for (int j2 = 0; j2 < 4; ++j2)
        gxb[j2] = make_uint4(w[j2 * 4], w[j2 * 4 + 1], w[j2 * 4 + 2], w[j2 * 4 + 3]);
    }
    const uint4* gB = (const uint4*)(B2c + (size_t)nt * 128 * 64);
    uint4* lB = (uint4*)(AB + 8192);
    #pragma unroll
    for (int j = 0; j < 4; ++j) {
      int q = j * 256 + tid;
      int qs = (q & ~7) | ((q & 7) ^ ((q >> 3) & 7));
      lB[qs] = gB[q];
    }
  }
  __syncthreads();

  f32x4 acc[4][4] = {};
  {
    const u16* Al = AB;
    const u16* Bl = AB + 8192;
    #pragma unroll
    for (int kk = 0; kk < 2; ++kk) {
      bf16x8 af[4], bfr[4];
      #pragma unroll
      for (int i = 0; i < 4; ++i) {
        int row = wr * 64 + i * 16 + lrow;
        af[i] = *(const bf16x8*)&Al[row * 64 + (((kk * 4 + hi4) ^ (row & 7)) << 3)];
      }
      #pragma unroll
      for (int j = 0; j < 4; ++j) {
        int row = wcol * 64 + j * 16 + lrow;
        bfr[j] = *(const bf16x8*)&Bl[row * 64 + (((kk * 4 + hi4) ^ (row & 7)) << 3)];
      }
      #pragma unroll
      for (int i = 0; i < 4; ++i)
        #pragma unroll
        for (int j = 0; j < 4; ++j)
          acc[i][j] = __builtin_amdgcn_mfma_f32_16x16x32_bf16(af[i], bfr[j], acc[i][j], 0, 0, 0);
    }
  }
  __syncthreads();   // staging reads done -> cvl overwrite safe (MODE 1)

  // ---- activation + in-register segment summaries (+ cvl store in MODE 1)
  #pragma unroll
  for (int jp = 0; jp < 2; ++jp) {
    const int dl = (wcol * 2 + jp) * 16 + lrow;     // 0..63
    const int d = nt * 64 + dl;
    #pragma unroll
    for (int sl = 0; sl < 2; ++sl) {
      float Cr[2], Vr[2];
      #pragma unroll
      for (int ii = 0; ii < 2; ++ii) {
        const int i = sl * 2 + ii;
        float C = 1.f, V = 0.f;
        #pragma unroll
        for (int r = 0; r < 4; ++r) {
          float cc, vvv;
          act_cv(acc[i][2 * jp + 0][r], acc[i][2 * jp + 1][r], cc, vvv);
          if (MODE == 1) {
            __half2 p = __floats2half2_rn(cc, vvv);
            int row = wr * 64 + i * 16 + hi4 * 4 + r;
            cvl[cvs(row, dl)] = *(const u32*)&p;
          }
          V = fmaf(cc, V, vvv);
          C *= cc;
        }
        comb_step(C, V, 16, ln);    // rows +0..3 | +4..7
        comb_step(C, V, 32, ln);    // rows +0..7 | +8..15
        Cr[ii] = C; Vr[ii] = V;
      }
      float Cs = Cr[0] * Cr[1];
      float Vs = fmaf(Cr[1], Vr[0], Vr[1]);
      if (hi4 == 0) {
        int seg = ck * 4 + wr * 2 + sl;
        SegC[(size_t)seg * DI + d] = Cs;
        SegV[(size_t)seg * DI + d] = Vs;
      }
    }
  }

  if (MODE == 1) {
    __syncthreads();
    uint4* dst = (uint4*)(cvg + (size_t)blockIdx.x * 8192);
    const uint4* src = (const uint4*)cvl;
    #pragma unroll
    for (int j = 0; j < 8; ++j) dst[j * 256 + tid] = src[j * 256 + tid];
  }
}

// ------- cross-segment carry scan; converts SegVH: V -> Hin in place -------
__global__ __launch_bounds__(128) void scan_carry(const float* __restrict__ SegC,
                                                  float* __restrict__ SegVH) {
  const int b = blockIdx.x / 6, dc = blockIdx.x % 6;
  const int d = dc * 128 + threadIdx.x;
  const size_t base = (size_t)b * SEGB * DI + d;
  float carry = 0.f;
  for (int q0 = 0; q0 < SEGB; q0 += 16) {
    float c16[16], v16[16];
    #pragma unroll
    for (int j = 0; j < 16; ++j) {
      size_t idx = base + (size_t)(q0 + j) * DI;
      c16[j] = SegC[idx];
      v16[j] = SegVH[idx];
    }
    #pragma unroll
    for (int j = 0; j < 16; ++j) {
      size_t idx = base + (size_t)(q0 + j) * DI;
      SegVH[idx] = carry;
      carry = fmaf(c16[j], carry, v16[j]);
    }
  }
}

// ======== PASS 2 (cv path): load cv tile + carried apply + reduce =========
__global__ __launch_bounds__(256) void fused_p2cv(
    const u32* __restrict__ cvg, const float* __restrict__ Hin,
    const float* __restrict__ wcomb, float* __restrict__ part) {
  __shared__ __align__(16) u32 cvl[8192];
  const int tid = threadIdx.x, wv = tid >> 6, ln = tid & 63;
  const int nt = blockIdx.x % DTILES, ck = blockIdx.x / DTILES;
  const int m0 = ck * CL;
  {
    const uint4* src = (const uint4*)(cvg + (size_t)blockIdx.x * 8192);
    uint4* dst = (uint4*)cvl;
    #pragma unroll
    for (int j = 0; j < 8; ++j) dst[j * 256 + tid] = src[j * 256 + tid];
  }
  const int seg = ck * 4 + wv;
  float h = Hin[(size_t)seg * DI + nt * 64 + ln];
  const float wd = wcomb[nt * 64 + ln];
  __syncthreads();
  #pragma unroll 4
  for (int tt = 0; tt < 32; ++tt) {
    const int t = wv * 32 + tt;
    u32 u = cvl[cvs(t, ln)];
    float hn;
    asm("v_fma_mix_f32 %0, %1, %2, %1 op_sel:[0,0,1] op_sel_hi:[1,0,1]"
        : "=v"(hn) : "v"(u), "v"(h));
    h = hn;
    float pv = h * wd;
    cvl[t * 64 + ((ln + t) & 63)] = __float_as_uint(pv);
  }
  __syncthreads();
  const int row = tid >> 1, half = tid & 1;
  float s = 0.f;
  #pragma unroll 8
  for (int jj = 0; jj < 32; ++jj) {
    int idx = (half * 32 + jj + row) & 63;
    s += __uint_as_float(cvl[row * 64 + idx]);
  }
  s += __shfl_xor(s, 1);
  if (half == 0) part[(size_t)nt * M + m0 + row] = s;
}

// ======== PASS 2 (fallback): recompute GEMM+act, then apply (round-6) =====
__global__ __launch_bounds__(256) void fused_p2xb(
    const u16* __restrict__ xb, const u16* __restrict__ B2c,
    const float* __restrict__ Hin, const float* __restrict__ wcomb,
    float* __restrict__ part) {
  __shared__ __align__(16) u16 AB[16384];
  u32* cvl = (u32*)AB;

  const int tid = threadIdx.x, wv = tid >> 6, ln = tid & 63;
  const int nt = blockIdx.x % DTILES, ck = blockIdx.x / DTILES;
  const int m0 = ck * CL;
  const int wr = wv >> 1, wcol = wv & 1;
  const int lrow = ln & 15, hi4 = ln >> 4;

  {
    const uint4* gA = (const uint4*)(xb + (size_t)m0 * 64);
    const uint4* gB = (const uint4*)(B2c + (size_t)nt * 128 * 64);
    uint4* lA = (uint4*)AB;
    uint4* lB = (uint4*)(AB + 8192);
    #pragma unroll
    for (int j = 0; j < 4; ++j) {
      int q = j * 256 + tid;
      int qs = (q & ~7) | ((q & 7) ^ ((q >> 3) & 7));
      lA[qs] = gA[q];
      lB[qs] = gB[q];
    }
  }
  __syncthreads();

  f32x4 acc[4][4] = {};
  {
    const u16* Al = AB;
    const u16* Bl = AB + 8192;
    #pragma unroll
    for (int kk = 0; kk < 2; ++kk) {
      bf16x8 af[4], bfr[4];
      #pragma unroll
      for (int i = 0; i < 4; ++i) {
        int row = wr * 64 + i * 16 + lrow;
        af[i] = *(const bf16x8*)&Al[row * 64 + (((kk * 4 + hi4) ^ (row & 7)) << 3)];
      }
      #pragma unroll
      for (int j = 0; j < 4; ++j) {
        int row = wcol * 64 + j * 16 + lrow;
        bfr[j] = *(const bf16x8*)&Bl[row * 64 + (((kk * 4 + hi4) ^ (row & 7)) << 3)];
      }
      #pragma unroll
      for (int i = 0; i < 4; ++i)
        #pragma unroll
        for (int j = 0; j < 4; ++j)
          acc[i][j] = __builtin_amdgcn_mfma_f32_16x16x32_bf16(af[i], bfr[j], acc[i][j], 0, 0, 0);
    }
  }
  __syncthreads();

  #pragma unroll
  for (int i = 0; i < 4; ++i)
    #pragma unroll
    for (int jp = 0; jp < 2; ++jp) {
      const int dl = (wcol * 2 + jp) * 16 + lrow;
      #pragma unroll
      for (int r = 0; r < 4; ++r) {
        int row = wr * 64 + i * 16 + hi4 * 4 + r;
        float cc, vvv;
        act_cv(acc[i][2 * jp + 0][r], acc[i][2 * jp + 1][r], cc, vvv);
        __half2 p = __floats2half2_rn(cc, vvv);
        cvl[cvs(row, dl)] = *(const u32*)&p;
      }
    }
  __syncthreads();

  const int seg = ck * 4 + wv;
  float h = Hin[(size_t)seg * DI + nt * 64 + ln];
  const float wd = wcomb[nt * 64 + ln];
  #pragma unroll 4
  for (int tt = 0; tt < 32; ++tt) {
    const int t = wv * 32 + tt;
    u32 u = cvl[cvs(t, ln)];
    float hn;
    asm("v_fma_mix_f32 %0, %1, %2, %1 op_sel:[0,0,1] op_sel_hi:[1,0,1]"
        : "=v"(hn) : "v"(u), "v"(h));
    h = hn;
    float pv = h * wd;
    cvl[t * 64 + ((ln + t) & 63)] = __float_as_uint(pv);
  }
  __syncthreads();
  const int row = tid >> 1, half = tid & 1;
  float s = 0.f;
  #pragma unroll 8
  for (int jj = 0; jj < 32; ++jj) {
    int idx = (half * 32 + jj + row) & 63;
    s += __uint_as_float(cvl[row * 64 + idx]);
  }
  s += __shfl_xor(s, 1);
  if (half == 0) part[(size_t)nt * M + m0 + row] = s;
}

// ---------------- final: sum 12 d-tile partials ----------------
__global__ __launch_bounds__(256) void reduce12(const float* __restrict__ part,
                                                float* __restrict__ out) {
  int i = blockIdx.x * 256 + threadIdx.x;
  float s = 0.f;
  #pragma unroll
  for (int w = 0; w < DTILES; ++w) s += part[(size_t)w * M + i];
  out[i] = s;
}

// ---------------- launcher ----------------
extern "C" void kernel_launch(void* const* d_in, const int* in_sizes, int n_in,
                              void* d_out, int out_size, void* d_ws, size_t ws_size,
                              hipStream_t stream) {
  const float* x    = (const float*)d_in[0];
  const float* Win  = (const float*)d_in[1];
  const float* Whg  = (const float*)d_in[2];
  const float* Wout = (const float*)d_in[3];
  const float* Wfin = (const float*)d_in[4];
  float* out = (float*)d_out;
  char* ws = (char*)d_ws;

  u16*   B2c   = (u16*)(ws + OFF_B2C);
  float* wc    = (float*)(ws + OFF_WC);
  float* SegC  = (float*)(ws + OFF_SEGC);
  float* SegVH = (float*)(ws + OFF_SEGVH);
  float* part  = (float*)(ws + OFF_PART);
  const bool big = (ws_size >= NEED_CV);

  prep_b2c  <<<384, 256, 0, stream>>>(Win, Whg, B2c);
  prep_wcomb<<<192, 256, 0, stream>>>(Wout, Wfin, wc);
  if (big) {
    u32* cvg = (u32*)(ws + OFF_AUX);
    fused_p1<1><<<NBLK, 256, 0, stream>>>(x, B2c, SegC, SegVH, cvg, nullptr);
    scan_carry<<<96, 128, 0, stream>>>(SegC, SegVH);
    fused_p2cv<<<NBLK, 256, 0, stream>>>(cvg, SegVH, wc, part);
  } else {
    u16* xb = (u16*)(ws + OFF_AUX);
    fused_p1<0><<<NBLK, 256, 0, stream>>>(x, B2c, SegC, SegVH, nullptr, xb);
    scan_carry<<<96, 128, 0, stream>>>(SegC, SegVH);
    fused_p2xb<<<NBLK, 256, 0, stream>>>(xb, B2c, SegVH, wc, part);
  }
  reduce12<<<256, 256, 0, stream>>>(part, out);
}